// Round 4
// baseline (129.628 us; speedup 1.0000x reference)
//
#include <hip/hip_runtime.h>
#include <math.h>

#define HB 64      // batch
#define HD 1024    // hidden / input dim
#define KS 128     // K-slice per split-K block
#define XS 68      // padded LDS row stride (floats); keeps float4 reads aligned

typedef float f32x4 __attribute__((ext_vector_type(4)));

// ---------------------------------------------------------------------------
// Split-K register-tiled GEMM slice with register prefetch (double-buffered
// through VGPRs): P[b][m0+mj] = sum_{n=k0..k0+KS-1} X[b][n] * W[m][n]
// Block 256 thr, tile 64b x 64m, thread (bx=t>>4, my=t&15) owns 4b x 4m.
// LDS transposed (Xs[n][b], Ws[n][m]) -> fragment reads are ds_read_b128.
// P stores: 16-lane groups cover contiguous 64 floats (coalesced 256B).
// ---------------------------------------------------------------------------
__device__ __forceinline__ void splitk_tile(
    const float* __restrict__ X0, int noff,      // element n read as X0[b*HD + n - noff]
    const float* __restrict__ W, int K,
    int m0, int k0,
    float* __restrict__ P)                       // 65536-float slab
{
    __shared__ __align__(16) float Xs[32][XS];
    __shared__ __align__(16) float Ws[32][XS];
    const int t  = threadIdx.x;
    const int bx = t >> 4;      // 0..15: batch group
    const int my = t & 15;      // 0..15: m group
    float acc[4][4] = {};

    float4 xp[2], wp[2];
    // prefetch chunk 0
    #pragma unroll
    for (int i = 0; i < 2; ++i) {
        int u = t + 256 * i;
        int r = u >> 3, nq = u & 7;             // r: batch or m row, nq: float4 col
        xp[i] = *(const float4*)&X0[r * HD + (k0 - noff) + nq * 4];
        wp[i] = *(const float4*)&W[(long long)(m0 + r) * K + k0 + nq * 4];
    }

    for (int kc = 0; kc < KS; kc += 32) {
        // write prefetched chunk to LDS (transposed)
        #pragma unroll
        for (int i = 0; i < 2; ++i) {
            int u = t + 256 * i;
            int r = u >> 3, nq = u & 7;
            Xs[nq * 4 + 0][r] = xp[i].x; Xs[nq * 4 + 1][r] = xp[i].y;
            Xs[nq * 4 + 2][r] = xp[i].z; Xs[nq * 4 + 3][r] = xp[i].w;
            Ws[nq * 4 + 0][r] = wp[i].x; Ws[nq * 4 + 1][r] = wp[i].y;
            Ws[nq * 4 + 2][r] = wp[i].z; Ws[nq * 4 + 3][r] = wp[i].w;
        }
        __syncthreads();
        // issue next chunk's loads; consumed after the next barrier, so the
        // HBM latency hides under the 32x16-FMA compute below.
        if (kc + 32 < KS) {
            const int n0 = k0 + kc + 32;
            #pragma unroll
            for (int i = 0; i < 2; ++i) {
                int u = t + 256 * i;
                int r = u >> 3, nq = u & 7;
                xp[i] = *(const float4*)&X0[r * HD + (n0 - noff) + nq * 4];
                wp[i] = *(const float4*)&W[(long long)(m0 + r) * K + n0 + nq * 4];
            }
        }
        #pragma unroll
        for (int n = 0; n < 32; ++n) {
            float4 xv = *(const float4*)&Xs[n][bx * 4];
            float4 wv = *(const float4*)&Ws[n][my * 4];
            float xe[4] = {xv.x, xv.y, xv.z, xv.w};
            float we[4] = {wv.x, wv.y, wv.z, wv.w};
            #pragma unroll
            for (int i = 0; i < 4; ++i)
                #pragma unroll
                for (int j = 0; j < 4; ++j)
                    acc[i][j] = fmaf(xe[i], we[j], acc[i][j]);
        }
        __syncthreads();
    }
    #pragma unroll
    for (int i = 0; i < 4; ++i) {
        float4 o4 = make_float4(acc[i][0], acc[i][1], acc[i][2], acc[i][3]);
        *(float4*)&P[(bx * 4 + i) * HD + m0 + my * 4] = o4;
    }
}

// grid.x = 16 m-tiles; grid.y = 56 (gemm,split) units:
//   gy 0..23  : q/k/v (8 splits each, K=1024);  gy 24..55 : f/i (16 splits, K=2048)
__global__ __launch_bounds__(256) void qkvfi_splitk(
    const float* __restrict__ x, const float* __restrict__ h,
    const float* __restrict__ Wq, const float* __restrict__ Wk,
    const float* __restrict__ Wv, const float* __restrict__ Wf,
    const float* __restrict__ Wi, float* __restrict__ P)
{
    const int gy = blockIdx.y;
    const float* W; int K, split;
    if (gy < 24) {
        int g = gy >> 3; split = gy & 7; K = HD;
        W = (g == 0) ? Wq : (g == 1) ? Wk : Wv;
    } else {
        int tt = gy - 24; int g = tt >> 4; split = tt & 15; K = 2 * HD;
        W = g ? Wi : Wf;
    }
    const int k0 = split * KS;
    const float* X0; int noff;
    if (k0 < HD) { X0 = x; noff = 0; } else { X0 = h; noff = HD; }
    splitk_tile(X0, noff, W, K, blockIdx.x * 64, k0, P + (size_t)gy * (HB * HD));
}

__global__ __launch_bounds__(256) void out_splitk(
    const float* __restrict__ tr, const float* __restrict__ Wo,
    float* __restrict__ P2)
{
    const int split = blockIdx.y;   // 0..7
    splitk_tile(tr, 0, Wo, HD, blockIdx.x * 64, split * KS,
                P2 + (size_t)split * (HB * HD));
}

// Deterministic float4 partial reduction + bias + activation for q/k/v/f/i.
__global__ __launch_bounds__(256) void reduce_qkvfi(
    const float* __restrict__ P,
    const float* __restrict__ bq, const float* __restrict__ bk,
    const float* __restrict__ bv, const float* __restrict__ bfv,
    const float* __restrict__ biv,
    float* __restrict__ q, float* __restrict__ k, float* __restrict__ v,
    float* __restrict__ fg, float* __restrict__ ig)
{
    const int o4 = blockIdx.x * 256 + threadIdx.x;   // 0..81919 (float4 units)
    const int g  = o4 >> 14;                         // which gemm
    const int r4 = o4 & 16383;                       // float4 idx in [B,HD]
    const int m4 = r4 & 255;                         // float4 idx in row
    int base, ns, act; const float* bias; float* out;
    switch (g) {
        case 0:  base = 0;  ns = 8;  bias = bq;  out = q;  act = 0; break;
        case 1:  base = 8;  ns = 8;  bias = bk;  out = k;  act = 0; break;
        case 2:  base = 16; ns = 8;  bias = bv;  out = v;  act = 0; break;
        case 3:  base = 24; ns = 16; bias = bfv; out = fg; act = 1; break;
        default: base = 40; ns = 16; bias = biv; out = ig; act = 1; break;
    }
    float4 s = ((const float4*)bias)[m4];
    const float4* P4 = (const float4*)P;
    for (int i = 0; i < ns; ++i) {
        float4 p = P4[(size_t)(base + i) * 16384 + r4];
        s.x += p.x; s.y += p.y; s.z += p.z; s.w += p.w;
    }
    if (act) {
        s.x = 1.0f / (1.0f + expf(-s.x)); s.y = 1.0f / (1.0f + expf(-s.y));
        s.z = 1.0f / (1.0f + expf(-s.z)); s.w = 1.0f / (1.0f + expf(-s.w));
    }
    ((float4*)out)[r4] = s;
}

__global__ __launch_bounds__(256) void reduce_out(
    const float* __restrict__ P2, const float* __restrict__ bo,
    float* __restrict__ hnew)
{
    const int o4 = blockIdx.x * 256 + threadIdx.x;   // 0..16383
    const int m4 = o4 & 255;
    float4 s = ((const float4*)bo)[m4];
    const float4* P4 = (const float4*)P2;
    #pragma unroll
    for (int i = 0; i < 8; ++i) {
        float4 p = P4[(size_t)i * 16384 + o4];
        s.x += p.x; s.y += p.y; s.z += p.z; s.w += p.w;
    }
    ((float4*)hnew)[o4] = s;
}

// ---------------------------------------------------------------------------
// Fused C update + readout (the HBM-roofline kernel, 512 MB of traffic):
//   Cn[b,m,n] = f[b,m]*C[b,m,n] + (i[b,m]*k[b,m])*v[b,n]
//   tr[b,m]   = tanh( sum_n Cn[b,m,n] * q[b,n] )
// One wave per TWO consecutive rows (same b): 8 independent C-loads in
// flight per lane, q/v loaded once per pair. Non-temporal on C streams.
// ---------------------------------------------------------------------------
__global__ __launch_bounds__(256) void update_kernel(
    const float* __restrict__ C,
    const float* __restrict__ q, const float* __restrict__ k,
    const float* __restrict__ v, const float* __restrict__ fg,
    const float* __restrict__ ig,
    float* __restrict__ Cn, float* __restrict__ tr)
{
    const int wid  = threadIdx.x >> 6;
    const int lane = threadIdx.x & 63;
    const int pair = blockIdx.x * 4 + wid;      // 0 .. B*HD/2-1
    const int row0 = pair * 2;
    const int b    = row0 >> 10;
    const int m0   = row0 & (HD - 1);

    const float f0  = fg[b * HD + m0];
    const float f1  = fg[b * HD + m0 + 1];
    const float ik0 = ig[b * HD + m0] * k[b * HD + m0];
    const float ik1 = ig[b * HD + m0 + 1] * k[b * HD + m0 + 1];

    const f32x4*  C4 = (const f32x4*)C;
    const float4* V4 = (const float4*)v;
    const float4* Q4 = (const float4*)q;
    f32x4*        N4 = (f32x4*)Cn;

    const int base0 = row0 * (HD / 4);
    const int base1 = base0 + (HD / 4);
    const int vbase = b * (HD / 4);

    float r0 = 0.f, r1 = 0.f;
    #pragma unroll
    for (int j = 0; j < 4; ++j) {
        int o = lane + 64 * j;
        f32x4 c0 = __builtin_nontemporal_load(&C4[base0 + o]);
        f32x4 c1 = __builtin_nontemporal_load(&C4[base1 + o]);
        float4 v4 = V4[vbase + o];
        float4 q4 = Q4[vbase + o];
        f32x4 n0, n1;
        n0.x = fmaf(f0, c0.x, ik0 * v4.x); n0.y = fmaf(f0, c0.y, ik0 * v4.y);
        n0.z = fmaf(f0, c0.z, ik0 * v4.z); n0.w = fmaf(f0, c0.w, ik0 * v4.w);
        n1.x = fmaf(f1, c1.x, ik1 * v4.x); n1.y = fmaf(f1, c1.y, ik1 * v4.y);
        n1.z = fmaf(f1, c1.z, ik1 * v4.z); n1.w = fmaf(f1, c1.w, ik1 * v4.w);
        __builtin_nontemporal_store(n0, &N4[base0 + o]);
        __builtin_nontemporal_store(n1, &N4[base1 + o]);
        r0 += n0.x * q4.x + n0.y * q4.y + n0.z * q4.z + n0.w * q4.w;
        r1 += n1.x * q4.x + n1.y * q4.y + n1.z * q4.z + n1.w * q4.w;
    }
    #pragma unroll
    for (int off = 32; off; off >>= 1) {
        r0 += __shfl_xor(r0, off);
        r1 += __shfl_xor(r1, off);
    }
    if (lane == 0) {
        tr[row0]     = tanhf(r0);
        tr[row0 + 1] = tanhf(r1);
    }
}

extern "C" void kernel_launch(void* const* d_in, const int* in_sizes, int n_in,
                              void* d_out, int out_size, void* d_ws, size_t ws_size,
                              hipStream_t stream) {
    const float* x  = (const float*)d_in[0];
    const float* h  = (const float*)d_in[1];
    const float* C  = (const float*)d_in[2];
    const float* Wq = (const float*)d_in[3];
    const float* bq = (const float*)d_in[4];
    const float* Wk = (const float*)d_in[5];
    const float* bk = (const float*)d_in[6];
    const float* Wv = (const float*)d_in[7];
    const float* bv = (const float*)d_in[8];
    const float* Wf = (const float*)d_in[9];
    const float* bf = (const float*)d_in[10];
    const float* Wi = (const float*)d_in[11];
    const float* bi = (const float*)d_in[12];
    const float* Wo = (const float*)d_in[13];
    const float* bo = (const float*)d_in[14];

    float* outp = (float*)d_out;
    float* hnew = outp;                    // [B,HD]
    float* Cn   = outp + HB * HD;          // [B,HD,HD]

    const size_t SL = (size_t)HB * HD;     // 65536
    float* ws = (float*)d_ws;
    float* q  = ws + 0 * SL;
    float* k  = ws + 1 * SL;
    float* v  = ws + 2 * SL;
    float* fg = ws + 3 * SL;
    float* ig = ws + 4 * SL;
    float* tr = ws + 5 * SL;
    float* P  = ws + 6 * SL;               // 56 slabs
    float* P2 = ws + 62 * SL;              // 8 slabs

    qkvfi_splitk<<<dim3(16, 56), 256, 0, stream>>>(x, h, Wq, Wk, Wv, Wf, Wi, P);
    reduce_qkvfi<<<dim3(320), 256, 0, stream>>>(P, bq, bk, bv, bf, bi,
                                                q, k, v, fg, ig);
    update_kernel<<<dim3((HB * HD) / 8), 256, 0, stream>>>(
        C, q, k, v, fg, ig, Cn, tr);
    out_splitk<<<dim3(16, 8), 256, 0, stream>>>(tr, Wo, P2);
    reduce_out<<<dim3(64), 256, 0, stream>>>(P2, bo, hnew);
}